// Round 9
// baseline (604.237 us; speedup 1.0000x reference)
//
#include <hip/hip_runtime.h>
#include <hip/hip_bf16.h>
#include <hip/hip_fp16.h>

#define BATCH 16384
#define HID   2048
#define IND   784
#define INDP  896   // 784 padded to 14*64 (even # of 64-wide K-tiles)
#define OUTD  10

typedef _Float16 f16;
typedef __attribute__((ext_vector_type(8))) _Float16 f16x8;
typedef __attribute__((ext_vector_type(4))) float f32x4;

// ---- mask dtype detector (verified R5) -------------------------------------
__global__ void mask_detect(const unsigned char* __restrict__ p, int nbytes,
                            int* __restrict__ flags) {
    int acc = 0;
    for (int i = blockIdx.x * blockDim.x + threadIdx.x; i < nbytes;
         i += gridDim.x * blockDim.x) {
        unsigned char b = p[i];
        if (b > 1) acc |= 2;
        else if (b != 0 && (i & 3) != 0) acc |= 1;
    }
    if (acc) atomicOr(flags, acc);
}

__global__ void prep_cast(const float* __restrict__ W,
                          const void* __restrict__ Mk,
                          const int* __restrict__ flags,
                          f16* __restrict__ out,
                          int rin, int kin, int kout, int total) {
    int idx = blockIdx.x * blockDim.x + threadIdx.x;
    if (idx >= total) return;
    int r = idx / kout, c = idx - r * kout;
    float v = 0.f;
    if (r < rin && c < kin) {
        v = W[(size_t)r * kin + c];
        if (Mk) {
            size_t mi = (size_t)r * kin + c;
            bool byteMode = (*flags == 1);
            bool keep = byteMode ? (((const unsigned char*)Mk)[mi] != 0)
                                 : (((const unsigned int*)Mk)[mi] != 0u);
            if (!keep) v = 0.f;
        }
    }
    out[idx] = (f16)v;
}

__device__ __forceinline__ void gload_lds16(const f16* g, f16* l) {
    __builtin_amdgcn_global_load_lds(
        (const __attribute__((address_space(1))) unsigned int*)g,
        (__attribute__((address_space(3))) unsigned int*)l,
        16, 0, 0);
}

#define BAR()    __builtin_amdgcn_s_barrier()
#define SCHED()  __builtin_amdgcn_sched_barrier(0)
#define WAITV8() asm volatile("s_waitcnt vmcnt(8)" ::: "memory")
#define WAITL0() asm volatile("s_waitcnt lgkmcnt(0)" ::: "memory")

// ---- 256x256 8-phase GEMM, 4-wave 128x128 wave-tile (R9) -------------------
// Motivation: R7/R8 hit the combined MFMA+LDS occupancy wall (46%+44% busy,
// serialized) -- LDS traffic is set by cross-wave redundancy (2Mx4N: A x4,
// B x2 = 192 KB/K-tile). 2Mx2N wave grid (wave-tile 128x128) cuts it to
// 128 KB (-33%), MFMA:read ratio 2.67 -> 4.0. acc = 8x8 f32x4 = 256 regs ->
// __launch_bounds__(256,1), 1 wave/SIMD; in-wave prefetch (R8 schedule)
// covers LDS latency. Swizzle + ledger carried from R7/R8 (conflict-free,
// vmcnt(8)=2 panels at odd-phase ends; panels now 4 gload issues each).
template<bool RELU>
__global__ __launch_bounds__(256, 1) void gemm4w(
    const f16* __restrict__ A, const f16* __restrict__ B,
    const float* __restrict__ bias, f16* __restrict__ C,
    int N, int K) {
    __shared__ f16 As[2 * 2 * 256 * 32];
    __shared__ f16 Bs[2 * 2 * 256 * 32];

    int nbn = N >> 8;
    int nwg = gridDim.x;
    int cpx = nwg >> 3;                       // nwg % 8 == 0 here
    int bid = blockIdx.x;
    int swz = (bid & 7) * cpx + (bid >> 3);   // XCD-aware, bijective
    int bm = swz / nbn, bn = swz % nbn;

    int tid = threadIdx.x;
    int w = tid >> 6, lane = tid & 63;
    int wr = w >> 1, wc = w & 1;              // 2M x 2N wave grid
    int l15 = lane & 15, l4 = lane >> 4;

    const f16* Ag = A + (size_t)bm * 256 * K;
    const f16* Bg = B + (size_t)bn * 256 * K;

    // staging: call j, thread tid -> slot fs=j*256+tid -> row=j*64+(tid>>2),
    // s=tid&3; global col-slot = s ^ ((row>>1)&3)  (j-invariant since 64|j*64).
    int r0 = tid >> 2, s0 = tid & 3;
    int c0 = (s0 ^ ((r0 >> 1) & 3)) * 8;

    auto stageA = [&](int buf, int ks, int tk) {
        #pragma unroll
        for (int j = 0; j < 4; ++j)
            gload_lds16(Ag + (size_t)(j * 64 + r0) * K + tk * 64 + ks * 32 + c0,
                        As + (buf * 2 + ks) * 8192 + j * 2048 + w * 512);
    };
    auto stageB = [&](int buf, int ks, int tk) {
        #pragma unroll
        for (int j = 0; j < 4; ++j)
            gload_lds16(Bg + (size_t)(j * 64 + r0) * K + tk * 64 + ks * 32 + c0,
                        Bs + (buf * 2 + ks) * 8192 + j * 2048 + w * 512);
    };

    int rsw = (l4 ^ ((l15 >> 1) & 3)) * 8;    // swizzled read slot (f16 units)
    auto ldA = [&](f16x8 (&af)[4], int buf, int ks, int mh) {
        int base = (buf * 2 + ks) * 8192;
        #pragma unroll
        for (int m = 0; m < 4; ++m) {
            int row = wr * 128 + (mh * 4 + m) * 16 + l15;
            af[m] = *(const f16x8*)(As + base + row * 32 + rsw);
        }
    };
    auto ldB = [&](f16x8 (&bf)[8], int buf, int ks) {
        int base = (buf * 2 + ks) * 8192;
        #pragma unroll
        for (int n = 0; n < 8; ++n) {
            int row = wc * 128 + n * 16 + l15;
            bf[n] = *(const f16x8*)(Bs + base + row * 32 + rsw);
        }
    };

    f32x4 acc[8][8] = {};
    auto mma = [&](f16x8 (&af)[4], f16x8 (&bf)[8], int mh) {
        __builtin_amdgcn_s_setprio(1);
        #pragma unroll
        for (int m = 0; m < 4; ++m)
            #pragma unroll
            for (int n = 0; n < 8; ++n)
                acc[mh * 4 + m][n] = __builtin_amdgcn_mfma_f32_16x16x32_f16(
                    af[m], bf[n], acc[mh * 4 + m][n], 0, 0, 0);
        __builtin_amdgcn_s_setprio(0);
    };

    int NT = K >> 6, NI = NT >> 1;

    f16x8 A0[4], A1[4], B0[8], B1[8];

    // prologue: stage tile0 (4 panels) + tile1 A0,B0 (24 issues); drain tile0
    // (oldest 16) -> vmcnt(8); preload ph1 fragments.
    stageA(0, 0, 0); stageB(0, 0, 0); stageA(0, 1, 0); stageB(0, 1, 0);
    stageA(1, 0, 1); stageB(1, 0, 1);
    WAITV8(); SCHED(); BAR();
    ldA(A0, 0, 0, 0); ldB(B0, 0, 0);
    WAITL0(); SCHED();

    for (int it = 0; it < NI; ++it) {
        int t1 = 2 * it + 1, t2 = 2 * it + 2, t3 = 2 * it + 3;
        if (t2 >= NT) t2 = 0;   // tail: stage into retired panels, never used
        if (t3 >= NT) t3 = 0;

        // ph1: mma(0,0,mh0) | prefetch A1<-(0,0,mh1) | stage A(1,1)<-t1
        ldA(A1, 0, 0, 1); stageA(1, 1, t1); SCHED();
        mma(A0, B0, 0);
        WAITL0(); WAITV8(); SCHED(); BAR();
        // ph2: mma(0,0,mh1) | prefetch A0<-(0,1,mh0), B1<-(0,1) | stage B(1,1)<-t1
        ldA(A0, 0, 1, 0); ldB(B1, 0, 1); stageB(1, 1, t1); SCHED();
        mma(A1, B0, 1);
        WAITL0(); SCHED(); BAR();
        // ph3: mma(0,1,mh0) | prefetch A1<-(0,1,mh1) | stage A(0,0)<-t2
        ldA(A1, 0, 1, 1); stageA(0, 0, t2); SCHED();
        mma(A0, B1, 0);
        WAITL0(); WAITV8(); SCHED(); BAR();
        // ph4: mma(0,1,mh1) | prefetch A0<-(1,0,mh0), B0<-(1,0) | stage B(0,0)<-t2
        ldA(A0, 1, 0, 0); ldB(B0, 1, 0); stageB(0, 0, t2); SCHED();
        mma(A1, B1, 1);
        WAITL0(); SCHED(); BAR();
        // ph5: mma(1,0,mh0) | prefetch A1<-(1,0,mh1) | stage A(0,1)<-t2
        ldA(A1, 1, 0, 1); stageA(0, 1, t2); SCHED();
        mma(A0, B0, 0);
        WAITL0(); WAITV8(); SCHED(); BAR();
        // ph6: mma(1,0,mh1) | prefetch A0<-(1,1,mh0), B1<-(1,1) | stage B(0,1)<-t2
        ldA(A0, 1, 1, 0); ldB(B1, 1, 1); stageB(0, 1, t2); SCHED();
        mma(A1, B0, 1);
        WAITL0(); SCHED(); BAR();
        // ph7: mma(1,1,mh0) | prefetch A1<-(1,1,mh1) | stage A(1,0)<-t3
        ldA(A1, 1, 1, 1); stageA(1, 0, t3); SCHED();
        mma(A0, B1, 0);
        WAITL0(); WAITV8(); SCHED(); BAR();
        // ph8: mma(1,1,mh1) | prefetch A0<-(0,0,mh0), B0<-(0,0) | stage B(1,0)<-t3
        ldA(A0, 0, 0, 0); ldB(B0, 0, 0); stageB(1, 0, t3); SCHED();
        mma(A1, B1, 1);
        WAITL0(); SCHED(); BAR();
    }

    // epilogue: C/D layout col=lane&15, row=(lane>>4)*4+reg (m89/m91)
    #pragma unroll
    for (int nf = 0; nf < 8; ++nf) {
        int j = bn * 256 + wc * 128 + nf * 16 + l15;
        float bv = bias[j];
        #pragma unroll
        for (int mf = 0; mf < 8; ++mf) {
            int i0 = bm * 256 + wr * 128 + mf * 16 + l4 * 4;
            #pragma unroll
            for (int r = 0; r < 4; ++r) {
                float v = acc[mf][nf][r] + bv;
                if (RELU) v = fmaxf(v, 0.f);
                C[(size_t)(i0 + r) * N + j] = (f16)v;
            }
        }
    }
}

// ---- head: verified R5 128^2 kernel (Nout=10 guard, f32 out) ---------------
__global__ __launch_bounds__(256, 3) void gemm_head(
    const f16* __restrict__ A, const f16* __restrict__ B,
    const float* __restrict__ bias, float* __restrict__ C,
    int K, int Nout) {
    __shared__ f16 As[128 * 64];
    __shared__ f16 Bs[128 * 64];
    int bm = blockIdx.x;
    int t = threadIdx.x;
    int w = t >> 6, lane = t & 63;
    int wm = w >> 1, wn = w & 1;
    int l15 = lane & 15, l4 = lane >> 4;
    const f16* Ag = A + (size_t)bm * 128 * K;
    const f16* Bg = B;
    int rr = w * 8 + (lane >> 3);
    int cc = (lane & 7) * 8;
    f32x4 acc[4][4] = {};
    for (int k0 = 0; k0 < K; k0 += 64) {
        #pragma unroll
        for (int i = 0; i < 4; ++i)
            gload_lds16(Ag + (size_t)(i * 32 + rr) * K + k0 + cc, As + i * 2048 + w * 512);
        #pragma unroll
        for (int i = 0; i < 4; ++i)
            gload_lds16(Bg + (size_t)(i * 32 + rr) * K + k0 + cc, Bs + i * 2048 + w * 512);
        __syncthreads();
        #pragma unroll
        for (int ks = 0; ks < 2; ++ks) {
            f16x8 af[4], bfr[4];
            #pragma unroll
            for (int m = 0; m < 4; ++m)
                af[m] = *(const f16x8*)(As + (wm * 64 + m * 16 + l15) * 64 + ks * 32 + l4 * 8);
            #pragma unroll
            for (int n = 0; n < 4; ++n)
                bfr[n] = *(const f16x8*)(Bs + (wn * 64 + n * 16 + l15) * 64 + ks * 32 + l4 * 8);
            #pragma unroll
            for (int m = 0; m < 4; ++m)
                #pragma unroll
                for (int n = 0; n < 4; ++n)
                    acc[m][n] = __builtin_amdgcn_mfma_f32_16x16x32_f16(af[m], bfr[n], acc[m][n], 0, 0, 0);
        }
        __syncthreads();
    }
    #pragma unroll
    for (int n = 0; n < 4; ++n) {
        int j = wn * 64 + n * 16 + l15;
        bool jok = j < Nout;
        float bv = jok ? bias[j] : 0.f;
        #pragma unroll
        for (int m = 0; m < 4; ++m) {
            int i0 = bm * 128 + wm * 64 + m * 16 + l4 * 4;
            #pragma unroll
            for (int r = 0; r < 4; ++r) {
                if (jok) C[(size_t)(i0 + r) * Nout + j] = acc[m][n][r] + bv;
            }
        }
    }
}

extern "C" void kernel_launch(void* const* d_in, const int* in_sizes, int n_in,
                              void* d_out, int out_size, void* d_ws, size_t ws_size,
                              hipStream_t stream) {
    const float* x  = (const float*)d_in[0];
    const float* W1 = (const float*)d_in[1];
    const float* b1 = (const float*)d_in[2];
    const float* W2 = (const float*)d_in[3];
    const float* b2 = (const float*)d_in[4];
    const float* W3 = (const float*)d_in[5];
    const float* b3 = (const float*)d_in[6];
    const float* W4 = (const float*)d_in[7];
    const float* b4 = (const float*)d_in[8];
    const float* W5 = (const float*)d_in[9];
    const float* b5 = (const float*)d_in[10];
    const void* m1 = d_in[11];
    const void* m2 = d_in[12];
    const void* m3 = d_in[13];
    const void* m4 = d_in[14];

    char* ws = (char*)d_ws;
    size_t off = 0;
    auto alloc = [&](size_t b) { char* p = ws + off; off += (b + 255) & ~(size_t)255; return p; };
    f16* xb  = (f16*)alloc((size_t)BATCH * INDP * 2);
    f16* w1b = (f16*)alloc((size_t)HID * INDP * 2);
    f16* w2b = (f16*)alloc((size_t)HID * HID * 2);
    f16* w3b = (f16*)alloc((size_t)HID * HID * 2);
    f16* w4b = (f16*)alloc((size_t)HID * HID * 2);
    f16* w5b = (f16*)alloc((size_t)128 * HID * 2);
    f16* h1  = (f16*)alloc((size_t)BATCH * HID * 2);
    f16* h2  = (f16*)alloc((size_t)BATCH * HID * 2);
    int* flags = (int*)alloc(256);

    hipMemsetAsync(flags, 0, sizeof(int), stream);
    mask_detect<<<64, 256, 0, stream>>>((const unsigned char*)m1, 262144, flags);

    auto prep = [&](const float* src, const void* mk, f16* dst,
                    int rin, int kin, int kout, int rout) {
        int total = rout * kout;
        prep_cast<<<(total + 255) / 256, 256, 0, stream>>>(src, mk, flags, dst,
                                                           rin, kin, kout, total);
    };
    prep(x,  nullptr, xb,  BATCH, IND, INDP, BATCH);
    prep(W1, m1,      w1b, HID,   IND, INDP, HID);
    prep(W2, m2,      w2b, HID,   HID, HID,  HID);
    prep(W3, m3,      w3b, HID,   HID, HID,  HID);
    prep(W4, m4,      w4b, HID,   HID, HID,  HID);
    prep(W5, nullptr, w5b, OUTD,  HID, HID,  128);

    int g4 = (BATCH / 256) * (HID / 256);   // 64 * 8 = 512 blocks
    gemm4w<true><<<g4, 256, 0, stream>>>(xb, w1b, b1, h1, HID, INDP);
    gemm4w<true><<<g4, 256, 0, stream>>>(h1, w2b, b2, h2, HID, HID);
    gemm4w<true><<<g4, 256, 0, stream>>>(h2, w3b, b3, h1, HID, HID);
    gemm4w<true><<<g4, 256, 0, stream>>>(h1, w4b, b4, h2, HID, HID);
    gemm_head<<<BATCH / 128, 256, 0, stream>>>(h2, w5b, b5, (float*)d_out, HID, OUTD);
}

// Round 10
// 538.879 us; speedup vs baseline: 1.1213x; 1.1213x over previous
//
#include <hip/hip_runtime.h>
#include <hip/hip_bf16.h>
#include <hip/hip_fp16.h>

#define BATCH 16384
#define HID   2048
#define IND   784
#define INDP  896   // 784 padded to 14*64 (even # of 64-wide K-tiles)
#define OUTD  10

typedef _Float16 f16;
typedef __attribute__((ext_vector_type(8))) _Float16 f16x8;
typedef __attribute__((ext_vector_type(4))) float f32x4;

// ---- mask dtype detector (verified R5) -------------------------------------
__global__ void mask_detect(const unsigned char* __restrict__ p, int nbytes,
                            int* __restrict__ flags) {
    int acc = 0;
    for (int i = blockIdx.x * blockDim.x + threadIdx.x; i < nbytes;
         i += gridDim.x * blockDim.x) {
        unsigned char b = p[i];
        if (b > 1) acc |= 2;
        else if (b != 0 && (i & 3) != 0) acc |= 1;
    }
    if (acc) atomicOr(flags, acc);
}

__global__ void prep_cast(const float* __restrict__ W,
                          const void* __restrict__ Mk,
                          const int* __restrict__ flags,
                          f16* __restrict__ out,
                          int rin, int kin, int kout, int total) {
    int idx = blockIdx.x * blockDim.x + threadIdx.x;
    if (idx >= total) return;
    int r = idx / kout, c = idx - r * kout;
    float v = 0.f;
    if (r < rin && c < kin) {
        v = W[(size_t)r * kin + c];
        if (Mk) {
            size_t mi = (size_t)r * kin + c;
            bool byteMode = (*flags == 1);
            bool keep = byteMode ? (((const unsigned char*)Mk)[mi] != 0)
                                 : (((const unsigned int*)Mk)[mi] != 0u);
            if (!keep) v = 0.f;
        }
    }
    out[idx] = (f16)v;
}

__device__ __forceinline__ void gload_lds16(const f16* g, f16* l) {
    __builtin_amdgcn_global_load_lds(
        (const __attribute__((address_space(1))) unsigned int*)g,
        (__attribute__((address_space(3))) unsigned int*)l,
        16, 0, 0);
}

#define BAR()    __builtin_amdgcn_s_barrier()
#define SCHED()  __builtin_amdgcn_sched_barrier(0)
#define WAITV4() asm volatile("s_waitcnt vmcnt(4)" ::: "memory")
#define WAITV8() asm volatile("s_waitcnt vmcnt(8)" ::: "memory")

// ---- 256x256 8-phase GEMM, depth-2 barrier-straddling frag pipeline (R10) --
// BM=BN=256, BK=64, 8 waves (2Mx4N), 512 thr. LDS: A/B x [buf][ks][256][32]
// f16 = 128 KiB. Panel = [256][32], staged by 2 gload_lds (R7 geometry).
// Swizzle (R7, conflict-free verified): 16B-slot ^= (row>>1)&3 both sides.
// R10: NO manual lgkm waits. Phase p: mma on frags ISSUED AT p-2 (compiler
// inserts the exact counted lgkmcnt before the mfma, two barriers after the
// read issue -> reads drain under other phases' MFMA); then issue reads for
// p+2 into the just-freed register set (SCHED pins the WAR order); then
// stage; counted vmcnt(4) at EVEN phase ends (drains stages 3-4 phases old:
// verified per-panel -- each read's panel is vmcnt-drained + barriered >= 1
// phase before its read issue; each restage follows the last consumption's
// phase-end barrier).
template<bool RELU>
__global__ __launch_bounds__(512, 2) void gemm8p(
    const f16* __restrict__ A, const f16* __restrict__ B,
    const float* __restrict__ bias, f16* __restrict__ C,
    int N, int K) {
    __shared__ f16 As[2 * 2 * 256 * 32];
    __shared__ f16 Bs[2 * 2 * 256 * 32];

    int nbn = N >> 8;
    int nwg = gridDim.x;
    int cpx = nwg >> 3;                       // nwg % 8 == 0 here
    int bid = blockIdx.x;
    int swz = (bid & 7) * cpx + (bid >> 3);   // XCD-aware, bijective
    int bm = swz / nbn, bn = swz % nbn;

    int tid = threadIdx.x;
    int w = tid >> 6, lane = tid & 63;
    int wr = w >> 2, wc = w & 3;
    int l15 = lane & 15, l4 = lane >> 4;

    const f16* Ag = A + (size_t)bm * 256 * K;
    const f16* Bg = B + (size_t)bn * 256 * K;

    int r0 = tid >> 2, s0 = tid & 3;
    int c0 = (s0 ^ ((r0 >> 1) & 3)) * 8;
    int ldsw0 = (w * 64) * 8;
    int ldsw1 = (512 + w * 64) * 8;

    auto stageA = [&](int buf, int ks, int tk) {
        gload_lds16(Ag + (size_t)r0 * K + tk * 64 + ks * 32 + c0,
                    As + (buf * 2 + ks) * 8192 + ldsw0);
        gload_lds16(Ag + (size_t)(128 + r0) * K + tk * 64 + ks * 32 + c0,
                    As + (buf * 2 + ks) * 8192 + ldsw1);
    };
    auto stageB = [&](int buf, int ks, int tk) {
        gload_lds16(Bg + (size_t)r0 * K + tk * 64 + ks * 32 + c0,
                    Bs + (buf * 2 + ks) * 8192 + ldsw0);
        gload_lds16(Bg + (size_t)(128 + r0) * K + tk * 64 + ks * 32 + c0,
                    Bs + (buf * 2 + ks) * 8192 + ldsw1);
    };

    int rsw = (l4 ^ ((l15 >> 1) & 3)) * 8;    // swizzled read slot (f16 units)
    auto ldA = [&](f16x8 (&af)[4], int buf, int ks, int mh) {
        int base = (buf * 2 + ks) * 8192;
        #pragma unroll
        for (int m = 0; m < 4; ++m) {
            int row = wr * 128 + (mh * 4 + m) * 16 + l15;
            af[m] = *(const f16x8*)(As + base + row * 32 + rsw);
        }
    };
    auto ldB = [&](f16x8 (&bf)[4], int buf, int ks) {
        int base = (buf * 2 + ks) * 8192;
        #pragma unroll
        for (int n = 0; n < 4; ++n) {
            int row = wc * 64 + n * 16 + l15;
            bf[n] = *(const f16x8*)(Bs + base + row * 32 + rsw);
        }
    };

    f32x4 acc[8][4] = {};
    auto mma = [&](f16x8 (&af)[4], f16x8 (&bf)[4], int mh) {
        __builtin_amdgcn_s_setprio(1);
        #pragma unroll
        for (int m = 0; m < 4; ++m)
            #pragma unroll
            for (int n = 0; n < 4; ++n)
                acc[mh * 4 + m][n] = __builtin_amdgcn_mfma_f32_16x16x32_f16(
                    af[m], bf[n], acc[mh * 4 + m][n], 0, 0, 0);
        __builtin_amdgcn_s_setprio(0);
    };

    int NT = K >> 6, NI = NT >> 1;

    // frag sets: Aa (odd phases / mh0), Ab (even / mh1); Ba, Bb alternate
    // (B issued at odd phases for the odd/even pair two phases on).
    f16x8 Aa[4], Ab[4], Ba[4], Bb[4];

    // prologue: stage (0,0),(0,1),(1,0); drain (0,0) -> vmcnt(8); BAR;
    // preload p1/p2 frags from (0,0); drain (0,1) -> vmcnt(4); BAR.
    // Entering loop: outstanding = A(1,0),B(1,0) = 4  (steady state).
    stageA(0, 0, 0); stageB(0, 0, 0); stageA(0, 1, 0); stageB(0, 1, 0);
    stageA(1, 0, 1); stageB(1, 0, 1);
    WAITV8(); SCHED(); BAR();
    ldA(Aa, 0, 0, 0); ldB(Bb, 0, 0); ldA(Ab, 0, 0, 1);
    WAITV4(); SCHED(); BAR();

    for (int it = 0; it < NI; ++it) {
        int t1 = 2 * it + 1, t2 = 2 * it + 2, t3 = 2 * it + 3;
        if (t2 >= NT) t2 = 0;   // tail: stage into retired panels, never used
        if (t3 >= NT) t3 = 0;

        // p1: mma (0,0,mh0)[Aa,Bb] | read p3: Aa<-(0,1,m0), Ba<-(0,1) | stage A(1,1)<-t1
        mma(Aa, Bb, 0); SCHED();
        ldA(Aa, 0, 1, 0); ldB(Ba, 0, 1); stageA(1, 1, t1);
        SCHED(); BAR();
        // p2: mma (0,0,mh1)[Ab,Bb] | read p4: Ab<-(0,1,m1) | stage B(1,1)<-t1 | vmcnt
        mma(Ab, Bb, 1); SCHED();
        ldA(Ab, 0, 1, 1); stageB(1, 1, t1);
        WAITV4(); SCHED(); BAR();
        // p3: mma (0,1,mh0)[Aa,Ba] | read p5: Aa<-(1,0,m0), Bb<-(1,0) | stage A(0,0)<-t2
        mma(Aa, Ba, 0); SCHED();
        ldA(Aa, 1, 0, 0); ldB(Bb, 1, 0); stageA(0, 0, t2);
        SCHED(); BAR();
        // p4: mma (0,1,mh1)[Ab,Ba] | read p6: Ab<-(1,0,m1) | stage B(0,0)<-t2 | vmcnt
        mma(Ab, Ba, 1); SCHED();
        ldA(Ab, 1, 0, 1); stageB(0, 0, t2);
        WAITV4(); SCHED(); BAR();
        // p5: mma (1,0,mh0)[Aa,Bb] | read p7: Aa<-(1,1,m0), Ba<-(1,1) | stage A(0,1)<-t2
        mma(Aa, Bb, 0); SCHED();
        ldA(Aa, 1, 1, 0); ldB(Ba, 1, 1); stageA(0, 1, t2);
        SCHED(); BAR();
        // p6: mma (1,0,mh1)[Ab,Bb] | read p8: Ab<-(1,1,m1) | stage B(0,1)<-t2 | vmcnt
        mma(Ab, Bb, 1); SCHED();
        ldA(Ab, 1, 1, 1); stageB(0, 1, t2);
        WAITV4(); SCHED(); BAR();
        // p7: mma (1,1,mh0)[Aa,Ba] | read p1': Aa<-(0,0,m0), Bb<-(0,0) | stage A(1,0)<-t3
        mma(Aa, Ba, 0); SCHED();
        ldA(Aa, 0, 0, 0); ldB(Bb, 0, 0); stageA(1, 0, t3);
        SCHED(); BAR();
        // p8: mma (1,1,mh1)[Ab,Ba] | read p2': Ab<-(0,0,m1) | stage B(1,0)<-t3 | vmcnt
        mma(Ab, Ba, 1); SCHED();
        ldA(Ab, 0, 0, 1); stageB(1, 0, t3);
        WAITV4(); SCHED(); BAR();
    }

    // epilogue: C/D layout col=lane&15, row=(lane>>4)*4+reg (m89/m91)
    #pragma unroll
    for (int nf = 0; nf < 4; ++nf) {
        int j = bn * 256 + wc * 64 + nf * 16 + l15;
        float bv = bias[j];
        #pragma unroll
        for (int mf = 0; mf < 8; ++mf) {
            int i0 = bm * 256 + wr * 128 + mf * 16 + l4 * 4;
            #pragma unroll
            for (int r = 0; r < 4; ++r) {
                float v = acc[mf][nf][r] + bv;
                if (RELU) v = fmaxf(v, 0.f);
                C[(size_t)(i0 + r) * N + j] = (f16)v;
            }
        }
    }
}

// ---- head: verified R5 128^2 kernel (Nout=10 guard, f32 out) ---------------
__global__ __launch_bounds__(256, 3) void gemm_head(
    const f16* __restrict__ A, const f16* __restrict__ B,
    const float* __restrict__ bias, float* __restrict__ C,
    int K, int Nout) {
    __shared__ f16 As[128 * 64];
    __shared__ f16 Bs[128 * 64];
    int bm = blockIdx.x;
    int t = threadIdx.x;
    int w = t >> 6, lane = t & 63;
    int wm = w >> 1, wn = w & 1;
    int l15 = lane & 15, l4 = lane >> 4;
    const f16* Ag = A + (size_t)bm * 128 * K;
    const f16* Bg = B;
    int rr = w * 8 + (lane >> 3);
    int cc = (lane & 7) * 8;
    f32x4 acc[4][4] = {};
    for (int k0 = 0; k0 < K; k0 += 64) {
        #pragma unroll
        for (int i = 0; i < 4; ++i)
            gload_lds16(Ag + (size_t)(i * 32 + rr) * K + k0 + cc, As + i * 2048 + w * 512);
        #pragma unroll
        for (int i = 0; i < 4; ++i)
            gload_lds16(Bg + (size_t)(i * 32 + rr) * K + k0 + cc, Bs + i * 2048 + w * 512);
        __syncthreads();
        #pragma unroll
        for (int ks = 0; ks < 2; ++ks) {
            f16x8 af[4], bfr[4];
            #pragma unroll
            for (int m = 0; m < 4; ++m)
                af[m] = *(const f16x8*)(As + (wm * 64 + m * 16 + l15) * 64 + ks * 32 + l4 * 8);
            #pragma unroll
            for (int n = 0; n < 4; ++n)
                bfr[n] = *(const f16x8*)(Bs + (wn * 64 + n * 16 + l15) * 64 + ks * 32 + l4 * 8);
            #pragma unroll
            for (int m = 0; m < 4; ++m)
                #pragma unroll
                for (int n = 0; n < 4; ++n)
                    acc[m][n] = __builtin_amdgcn_mfma_f32_16x16x32_f16(af[m], bfr[n], acc[m][n], 0, 0, 0);
        }
        __syncthreads();
    }
    #pragma unroll
    for (int n = 0; n < 4; ++n) {
        int j = wn * 64 + n * 16 + l15;
        bool jok = j < Nout;
        float bv = jok ? bias[j] : 0.f;
        #pragma unroll
        for (int m = 0; m < 4; ++m) {
            int i0 = bm * 128 + wm * 64 + m * 16 + l4 * 4;
            #pragma unroll
            for (int r = 0; r < 4; ++r) {
                if (jok) C[(size_t)(i0 + r) * Nout + j] = acc[m][n][r] + bv;
            }
        }
    }
}

extern "C" void kernel_launch(void* const* d_in, const int* in_sizes, int n_in,
                              void* d_out, int out_size, void* d_ws, size_t ws_size,
                              hipStream_t stream) {
    const float* x  = (const float*)d_in[0];
    const float* W1 = (const float*)d_in[1];
    const float* b1 = (const float*)d_in[2];
    const float* W2 = (const float*)d_in[3];
    const float* b2 = (const float*)d_in[4];
    const float* W3 = (const float*)d_in[5];
    const float* b3 = (const float*)d_in[6];
    const float* W4 = (const float*)d_in[7];
    const float* b4 = (const float*)d_in[8];
    const float* W5 = (const float*)d_in[9];
    const float* b5 = (const float*)d_in[10];
    const void* m1 = d_in[11];
    const void* m2 = d_in[12];
    const void* m3 = d_in[13];
    const void* m4 = d_in[14];

    char* ws = (char*)d_ws;
    size_t off = 0;
    auto alloc = [&](size_t b) { char* p = ws + off; off += (b + 255) & ~(size_t)255; return p; };
    f16* xb  = (f16*)alloc((size_t)BATCH * INDP * 2);
    f16* w1b = (f16*)alloc((size_t)HID * INDP * 2);
    f16* w2b = (f16*)alloc((size_t)HID * HID * 2);
    f16* w3b = (f16*)alloc((size_t)HID * HID * 2);
    f16* w4b = (f16*)alloc((size_t)HID * HID * 2);
    f16* w5b = (f16*)alloc((size_t)128 * HID * 2);
    f16* h1  = (f16*)alloc((size_t)BATCH * HID * 2);
    f16* h2  = (f16*)alloc((size_t)BATCH * HID * 2);
    int* flags = (int*)alloc(256);

    hipMemsetAsync(flags, 0, sizeof(int), stream);
    mask_detect<<<64, 256, 0, stream>>>((const unsigned char*)m1, 262144, flags);

    auto prep = [&](const float* src, const void* mk, f16* dst,
                    int rin, int kin, int kout, int rout) {
        int total = rout * kout;
        prep_cast<<<(total + 255) / 256, 256, 0, stream>>>(src, mk, flags, dst,
                                                           rin, kin, kout, total);
    };
    prep(x,  nullptr, xb,  BATCH, IND, INDP, BATCH);
    prep(W1, m1,      w1b, HID,   IND, INDP, HID);
    prep(W2, m2,      w2b, HID,   HID, HID,  HID);
    prep(W3, m3,      w3b, HID,   HID, HID,  HID);
    prep(W4, m4,      w4b, HID,   HID, HID,  HID);
    prep(W5, nullptr, w5b, OUTD,  HID, HID,  128);

    int g8 = (BATCH / 256) * (HID / 256);   // 64 * 8 = 512 blocks
    gemm8p<true><<<g8, 512, 0, stream>>>(xb, w1b, b1, h1, HID, INDP);
    gemm8p<true><<<g8, 512, 0, stream>>>(h1, w2b, b2, h2, HID, HID);
    gemm8p<true><<<g8, 512, 0, stream>>>(h2, w3b, b3, h1, HID, HID);
    gemm8p<true><<<g8, 512, 0, stream>>>(h1, w4b, b4, h2, HID, HID);
    gemm_head<<<BATCH / 128, 256, 0, stream>>>(h2, w5b, b5, (float*)d_out, HID, OUTD);
}

// Round 11
// 514.381 us; speedup vs baseline: 1.1747x; 1.0476x over previous
//
#include <hip/hip_runtime.h>
#include <hip/hip_bf16.h>
#include <hip/hip_fp16.h>

#define BATCH 16384
#define HID   2048
#define IND   784
#define INDP  896   // 784 padded to 14*64 (even # of 64-wide K-tiles)
#define OUTD  10

typedef _Float16 f16;
typedef __attribute__((ext_vector_type(8))) _Float16 f16x8;
typedef __attribute__((ext_vector_type(4))) _Float16 f16x4;
typedef __attribute__((ext_vector_type(4))) float f32x4;

// ---- mask dtype detector (verified R5) -------------------------------------
__global__ void mask_detect(const unsigned char* __restrict__ p, int nbytes,
                            int* __restrict__ flags) {
    int acc = 0;
    for (int i = blockIdx.x * blockDim.x + threadIdx.x; i < nbytes;
         i += gridDim.x * blockDim.x) {
        unsigned char b = p[i];
        if (b > 1) acc |= 2;
        else if (b != 0 && (i & 3) != 0) acc |= 1;
    }
    if (acc) atomicOr(flags, acc);
}

// ---- vectorized x4 cast+mask (R11: G13 — scalar loads were 2x slower) ------
// kin, kout both divisible by 4. Pad region (r>=rin or c>=kin) = 0.
__global__ void prep_cast4(const float* __restrict__ W,
                           const void* __restrict__ Mk,
                           const int* __restrict__ flags,
                           f16* __restrict__ out,
                           int rin, int kin, int kout, int total4) {
    int idx = blockIdx.x * blockDim.x + threadIdx.x;
    if (idx >= total4) return;
    int k4 = kout >> 2;
    int r = idx / k4, c = (idx - r * k4) << 2;
    f16x4 o = {};
    if (r < rin && c < kin) {
        float4 v = *(const float4*)(W + (size_t)r * kin + c);
        float vv0 = v.x, vv1 = v.y, vv2 = v.z, vv3 = v.w;
        if (Mk) {
            if (*flags == 1) {
                uchar4 m = *(const uchar4*)((const unsigned char*)Mk + (size_t)r * kin + c);
                if (!m.x) vv0 = 0.f; if (!m.y) vv1 = 0.f;
                if (!m.z) vv2 = 0.f; if (!m.w) vv3 = 0.f;
            } else {
                uint4 m = *(const uint4*)((const unsigned int*)Mk + (size_t)r * kin + c);
                if (!m.x) vv0 = 0.f; if (!m.y) vv1 = 0.f;
                if (!m.z) vv2 = 0.f; if (!m.w) vv3 = 0.f;
            }
        }
        o[0] = (f16)vv0; o[1] = (f16)vv1; o[2] = (f16)vv2; o[3] = (f16)vv3;
    }
    *(f16x4*)(out + (size_t)r * kout + c) = o;
}

__device__ __forceinline__ void gload_lds16(const f16* g, f16* l) {
    __builtin_amdgcn_global_load_lds(
        (const __attribute__((address_space(1))) unsigned int*)g,
        (__attribute__((address_space(3))) unsigned int*)l,
        16, 0, 0);
}

#define BAR()    __builtin_amdgcn_s_barrier()
#define SCHED()  __builtin_amdgcn_sched_barrier(0)
#define WAITV4() asm volatile("s_waitcnt vmcnt(4)" ::: "memory")
#define WAITV8() asm volatile("s_waitcnt vmcnt(8)" ::: "memory")

// ---- 256x256 8-phase GEMM, depth-2 straddling pipeline (R10) ---------------
// R11 delta: REMOVED the post-mma SCHED() pins (m141/m201: sched_barrier(0)
// order-pinning defeats compiler interleave of ds_read issue among the MFMA
// stream; frag-reg WAR is enforced by regalloc). vmcnt ledger and barrier
// structure unchanged from R10 (verified stall-free, conflicts = 0).
template<bool RELU>
__global__ __launch_bounds__(512, 2) void gemm8p(
    const f16* __restrict__ A, const f16* __restrict__ B,
    const float* __restrict__ bias, f16* __restrict__ C,
    int N, int K) {
    __shared__ f16 As[2 * 2 * 256 * 32];
    __shared__ f16 Bs[2 * 2 * 256 * 32];

    int nbn = N >> 8;
    int nwg = gridDim.x;
    int cpx = nwg >> 3;                       // nwg % 8 == 0 here
    int bid = blockIdx.x;
    int swz = (bid & 7) * cpx + (bid >> 3);   // XCD-aware, bijective
    int bm = swz / nbn, bn = swz % nbn;

    int tid = threadIdx.x;
    int w = tid >> 6, lane = tid & 63;
    int wr = w >> 2, wc = w & 3;
    int l15 = lane & 15, l4 = lane >> 4;

    const f16* Ag = A + (size_t)bm * 256 * K;
    const f16* Bg = B + (size_t)bn * 256 * K;

    int r0 = tid >> 2, s0 = tid & 3;
    int c0 = (s0 ^ ((r0 >> 1) & 3)) * 8;
    int ldsw0 = (w * 64) * 8;
    int ldsw1 = (512 + w * 64) * 8;

    auto stageA = [&](int buf, int ks, int tk) {
        gload_lds16(Ag + (size_t)r0 * K + tk * 64 + ks * 32 + c0,
                    As + (buf * 2 + ks) * 8192 + ldsw0);
        gload_lds16(Ag + (size_t)(128 + r0) * K + tk * 64 + ks * 32 + c0,
                    As + (buf * 2 + ks) * 8192 + ldsw1);
    };
    auto stageB = [&](int buf, int ks, int tk) {
        gload_lds16(Bg + (size_t)r0 * K + tk * 64 + ks * 32 + c0,
                    Bs + (buf * 2 + ks) * 8192 + ldsw0);
        gload_lds16(Bg + (size_t)(128 + r0) * K + tk * 64 + ks * 32 + c0,
                    Bs + (buf * 2 + ks) * 8192 + ldsw1);
    };

    int rsw = (l4 ^ ((l15 >> 1) & 3)) * 8;    // swizzled read slot (f16 units)
    auto ldA = [&](f16x8 (&af)[4], int buf, int ks, int mh) {
        int base = (buf * 2 + ks) * 8192;
        #pragma unroll
        for (int m = 0; m < 4; ++m) {
            int row = wr * 128 + (mh * 4 + m) * 16 + l15;
            af[m] = *(const f16x8*)(As + base + row * 32 + rsw);
        }
    };
    auto ldB = [&](f16x8 (&bf)[4], int buf, int ks) {
        int base = (buf * 2 + ks) * 8192;
        #pragma unroll
        for (int n = 0; n < 4; ++n) {
            int row = wc * 64 + n * 16 + l15;
            bf[n] = *(const f16x8*)(Bs + base + row * 32 + rsw);
        }
    };

    f32x4 acc[8][4] = {};
    auto mma = [&](f16x8 (&af)[4], f16x8 (&bf)[4], int mh) {
        __builtin_amdgcn_s_setprio(1);
        #pragma unroll
        for (int m = 0; m < 4; ++m)
            #pragma unroll
            for (int n = 0; n < 4; ++n)
                acc[mh * 4 + m][n] = __builtin_amdgcn_mfma_f32_16x16x32_f16(
                    af[m], bf[n], acc[mh * 4 + m][n], 0, 0, 0);
        __builtin_amdgcn_s_setprio(0);
    };

    int NT = K >> 6, NI = NT >> 1;

    f16x8 Aa[4], Ab[4], Ba[4], Bb[4];

    // prologue: stage (0,0),(0,1),(1,0); drain (0,0) -> vmcnt(8); BAR;
    // preload p1/p2 frags from (0,0); drain (0,1) -> vmcnt(4); BAR.
    stageA(0, 0, 0); stageB(0, 0, 0); stageA(0, 1, 0); stageB(0, 1, 0);
    stageA(1, 0, 1); stageB(1, 0, 1);
    WAITV8(); SCHED(); BAR();
    ldA(Aa, 0, 0, 0); ldB(Bb, 0, 0); ldA(Ab, 0, 0, 1);
    WAITV4(); SCHED(); BAR();

    for (int it = 0; it < NI; ++it) {
        int t1 = 2 * it + 1, t2 = 2 * it + 2, t3 = 2 * it + 3;
        if (t2 >= NT) t2 = 0;   // tail: stage into retired panels, never used
        if (t3 >= NT) t3 = 0;

        // p1: mma (0,0,mh0)[Aa,Bb] | read p3: Aa<-(0,1,m0), Ba<-(0,1) | stage A(1,1)<-t1
        mma(Aa, Bb, 0);
        ldA(Aa, 0, 1, 0); ldB(Ba, 0, 1); stageA(1, 1, t1);
        SCHED(); BAR();
        // p2: mma (0,0,mh1)[Ab,Bb] | read p4: Ab<-(0,1,m1) | stage B(1,1)<-t1 | vmcnt
        mma(Ab, Bb, 1);
        ldA(Ab, 0, 1, 1); stageB(1, 1, t1);
        WAITV4(); SCHED(); BAR();
        // p3: mma (0,1,mh0)[Aa,Ba] | read p5: Aa<-(1,0,m0), Bb<-(1,0) | stage A(0,0)<-t2
        mma(Aa, Ba, 0);
        ldA(Aa, 1, 0, 0); ldB(Bb, 1, 0); stageA(0, 0, t2);
        SCHED(); BAR();
        // p4: mma (0,1,mh1)[Ab,Ba] | read p6: Ab<-(1,0,m1) | stage B(0,0)<-t2 | vmcnt
        mma(Ab, Ba, 1);
        ldA(Ab, 1, 0, 1); stageB(0, 0, t2);
        WAITV4(); SCHED(); BAR();
        // p5: mma (1,0,mh0)[Aa,Bb] | read p7: Aa<-(1,1,m0), Ba<-(1,1) | stage A(0,1)<-t2
        mma(Aa, Bb, 0);
        ldA(Aa, 1, 1, 0); ldB(Ba, 1, 1); stageA(0, 1, t2);
        SCHED(); BAR();
        // p6: mma (1,0,mh1)[Ab,Bb] | read p8: Ab<-(1,1,m1) | stage B(0,1)<-t2 | vmcnt
        mma(Ab, Bb, 1);
        ldA(Ab, 1, 1, 1); stageB(0, 1, t2);
        WAITV4(); SCHED(); BAR();
        // p7: mma (1,1,mh0)[Aa,Ba] | read p1': Aa<-(0,0,m0), Bb<-(0,0) | stage A(1,0)<-t3
        mma(Aa, Ba, 0);
        ldA(Aa, 0, 0, 0); ldB(Bb, 0, 0); stageA(1, 0, t3);
        SCHED(); BAR();
        // p8: mma (1,1,mh1)[Ab,Ba] | read p2': Ab<-(0,0,m1) | stage B(1,0)<-t3 | vmcnt
        mma(Ab, Ba, 1);
        ldA(Ab, 0, 0, 1); stageB(1, 0, t3);
        WAITV4(); SCHED(); BAR();
    }

    // epilogue: C/D layout col=lane&15, row=(lane>>4)*4+reg (m89/m91)
    #pragma unroll
    for (int nf = 0; nf < 4; ++nf) {
        int j = bn * 256 + wc * 64 + nf * 16 + l15;
        float bv = bias[j];
        #pragma unroll
        for (int mf = 0; mf < 8; ++mf) {
            int i0 = bm * 256 + wr * 128 + mf * 16 + l4 * 4;
            #pragma unroll
            for (int r = 0; r < 4; ++r) {
                float v = acc[mf][nf][r] + bv;
                if (RELU) v = fmaxf(v, 0.f);
                C[(size_t)(i0 + r) * N + j] = (f16)v;
            }
        }
    }
}

// ---- head: verified R5 128^2 kernel (Nout=10 guard, f32 out) ---------------
__global__ __launch_bounds__(256, 3) void gemm_head(
    const f16* __restrict__ A, const f16* __restrict__ B,
    const float* __restrict__ bias, float* __restrict__ C,
    int K, int Nout) {
    __shared__ f16 As[128 * 64];
    __shared__ f16 Bs[128 * 64];
    int bm = blockIdx.x;
    int t = threadIdx.x;
    int w = t >> 6, lane = t & 63;
    int wm = w >> 1, wn = w & 1;
    int l15 = lane & 15, l4 = lane >> 4;
    const f16* Ag = A + (size_t)bm * 128 * K;
    const f16* Bg = B;
    int rr = w * 8 + (lane >> 3);
    int cc = (lane & 7) * 8;
    f32x4 acc[4][4] = {};
    for (int k0 = 0; k0 < K; k0 += 64) {
        #pragma unroll
        for (int i = 0; i < 4; ++i)
            gload_lds16(Ag + (size_t)(i * 32 + rr) * K + k0 + cc, As + i * 2048 + w * 512);
        #pragma unroll
        for (int i = 0; i < 4; ++i)
            gload_lds16(Bg + (size_t)(i * 32 + rr) * K + k0 + cc, Bs + i * 2048 + w * 512);
        __syncthreads();
        #pragma unroll
        for (int ks = 0; ks < 2; ++ks) {
            f16x8 af[4], bfr[4];
            #pragma unroll
            for (int m = 0; m < 4; ++m)
                af[m] = *(const f16x8*)(As + (wm * 64 + m * 16 + l15) * 64 + ks * 32 + l4 * 8);
            #pragma unroll
            for (int n = 0; n < 4; ++n)
                bfr[n] = *(const f16x8*)(Bs + (wn * 64 + n * 16 + l15) * 64 + ks * 32 + l4 * 8);
            #pragma unroll
            for (int m = 0; m < 4; ++m)
                #pragma unroll
                for (int n = 0; n < 4; ++n)
                    acc[m][n] = __builtin_amdgcn_mfma_f32_16x16x32_f16(af[m], bfr[n], acc[m][n], 0, 0, 0);
        }
        __syncthreads();
    }
    #pragma unroll
    for (int n = 0; n < 4; ++n) {
        int j = wn * 64 + n * 16 + l15;
        bool jok = j < Nout;
        float bv = jok ? bias[j] : 0.f;
        #pragma unroll
        for (int m = 0; m < 4; ++m) {
            int i0 = bm * 128 + wm * 64 + m * 16 + l4 * 4;
            #pragma unroll
            for (int r = 0; r < 4; ++r) {
                if (jok) C[(size_t)(i0 + r) * Nout + j] = acc[m][n][r] + bv;
            }
        }
    }
}

extern "C" void kernel_launch(void* const* d_in, const int* in_sizes, int n_in,
                              void* d_out, int out_size, void* d_ws, size_t ws_size,
                              hipStream_t stream) {
    const float* x  = (const float*)d_in[0];
    const float* W1 = (const float*)d_in[1];
    const float* b1 = (const float*)d_in[2];
    const float* W2 = (const float*)d_in[3];
    const float* b2 = (const float*)d_in[4];
    const float* W3 = (const float*)d_in[5];
    const float* b3 = (const float*)d_in[6];
    const float* W4 = (const float*)d_in[7];
    const float* b4 = (const float*)d_in[8];
    const float* W5 = (const float*)d_in[9];
    const float* b5 = (const float*)d_in[10];
    const void* m1 = d_in[11];
    const void* m2 = d_in[12];
    const void* m3 = d_in[13];
    const void* m4 = d_in[14];

    char* ws = (char*)d_ws;
    size_t off = 0;
    auto alloc = [&](size_t b) { char* p = ws + off; off += (b + 255) & ~(size_t)255; return p; };
    f16* xb  = (f16*)alloc((size_t)BATCH * INDP * 2);
    f16* w1b = (f16*)alloc((size_t)HID * INDP * 2);
    f16* w2b = (f16*)alloc((size_t)HID * HID * 2);
    f16* w3b = (f16*)alloc((size_t)HID * HID * 2);
    f16* w4b = (f16*)alloc((size_t)HID * HID * 2);
    f16* w5b = (f16*)alloc((size_t)128 * HID * 2);
    f16* h1  = (f16*)alloc((size_t)BATCH * HID * 2);
    f16* h2  = (f16*)alloc((size_t)BATCH * HID * 2);
    int* flags = (int*)alloc(256);

    hipMemsetAsync(flags, 0, sizeof(int), stream);
    mask_detect<<<64, 256, 0, stream>>>((const unsigned char*)m1, 262144, flags);

    auto prep = [&](const float* src, const void* mk, f16* dst,
                    int rin, int kin, int kout, int rout) {
        int total4 = rout * (kout >> 2);
        prep_cast4<<<(total4 + 255) / 256, 256, 0, stream>>>(src, mk, flags, dst,
                                                             rin, kin, kout, total4);
    };
    prep(x,  nullptr, xb,  BATCH, IND, INDP, BATCH);
    prep(W1, m1,      w1b, HID,   IND, INDP, HID);
    prep(W2, m2,      w2b, HID,   HID, HID,  HID);
    prep(W3, m3,      w3b, HID,   HID, HID,  HID);
    prep(W4, m4,      w4b, HID,   HID, HID,  HID);
    prep(W5, nullptr, w5b, OUTD,  HID, HID,  128);

    int g8 = (BATCH / 256) * (HID / 256);   // 64 * 8 = 512 blocks
    gemm8p<true><<<g8, 512, 0, stream>>>(xb, w1b, b1, h1, HID, INDP);
    gemm8p<true><<<g8, 512, 0, stream>>>(h1, w2b, b2, h2, HID, HID);
    gemm8p<true><<<g8, 512, 0, stream>>>(h2, w3b, b3, h1, HID, HID);
    gemm8p<true><<<g8, 512, 0, stream>>>(h1, w4b, b4, h2, HID, HID);
    gemm_head<<<BATCH / 128, 256, 0, stream>>>(h2, w5b, b5, (float*)d_out, HID, OUTD);
}